// Round 6
// baseline (533.209 us; speedup 1.0000x reference)
//
#include <hip/hip_runtime.h>

#define NB 15
#define NV 17          // focal, cp, 15 bins
#define BLOCK 256
#define BIGGRID 2048   // 2048 blocks * 4 waves/block = 8192 waves

// ws layout: partials[j * grid + block] j in [0,NV), then a 4-byte counter.
// j=0: focal sum, j=1: cp sum, j=2..16: per-bin sum(t - p)

typedef float f32x4 __attribute__((ext_vector_type(4)));
typedef int   i32x4 __attribute__((ext_vector_type(4)));

__device__ __forceinline__ void process_elem(float pk, float uk, int tk,
                                             float& facc, float& cacc,
                                             float* bins)
{
    bool pos = (tk == 1);

    // focal: -alpha * (1-pt)^2 * ln(pt + 1e-12); ln2 folded into alpha
    float pt  = pos ? pk : 1.0f - pk;
    float om  = 1.0f - pt;
    float l2  = __log2f(pt + 1e-12f);
    float f   = om * om * l2;
    float na  = pos ? -0.69314718055994531f : -1.38629436111989062f;
    facc = fmaf(f, na, facc);

    // calibration penalty, gate rewritten on pt:
    //   pos: pk<0.7 <=> pt<0.7 ; neg: pk>0.7 <=> pt<0.3
    float thr = pos ? 0.7f : 0.3f;
    float s   = pos ? uk : 1.0f - uk;
    float pen = (pt < thr) ? s * s : 0.0f;
    cacc += pen;

    // ECE histogram into register bins (exact ceil form preserved)
    int b = (int)ceilf(pk * 15.0f) - 1;
    b = min(max(b, 0), NB - 1);
    float v = (pos ? 1.0f : 0.0f) - pk;
    #pragma unroll
    for (int j = 0; j < NB; ++j)
        bins[j] += (b == j) ? v : 0.0f;
}

__global__ void fcl_init(unsigned int* __restrict__ counter)
{
    *counter = 0u;
}

__global__ __launch_bounds__(BLOCK) void fcl_fused(
    const float* __restrict__ p_hat,
    const float* __restrict__ u_hat,
    const int*   __restrict__ targets,
    float* __restrict__ partials,
    unsigned int* __restrict__ counter,
    float* __restrict__ out,
    float inv_n, int n4, int n, int grid)
{
    float bins[NB];
    #pragma unroll
    for (int j = 0; j < NB; ++j) bins[j] = 0.0f;
    float facc = 0.0f, cacc = 0.0f;

    const f32x4* __restrict__ p4 = (const f32x4*)p_hat;
    const f32x4* __restrict__ u4 = (const f32x4*)u_hat;
    const i32x4* __restrict__ t4 = (const i32x4*)targets;

    const int stride = grid * BLOCK;
    int i = blockIdx.x * BLOCK + threadIdx.x;

    // 2x unrolled grid-stride convoy; NONTEMPORAL loads bypass the L1,
    // which provides zero reuse here and whose sets are aliased by the
    // three same-size p/u/t streams (suspected request-path throttle).
    for (; i + stride < n4; i += 2 * stride) {
        f32x4 p0 = __builtin_nontemporal_load(p4 + i);
        f32x4 p1 = __builtin_nontemporal_load(p4 + i + stride);
        f32x4 u0 = __builtin_nontemporal_load(u4 + i);
        f32x4 u1 = __builtin_nontemporal_load(u4 + i + stride);
        i32x4 t0 = __builtin_nontemporal_load(t4 + i);
        i32x4 t1 = __builtin_nontemporal_load(t4 + i + stride);
        #pragma unroll
        for (int k = 0; k < 4; ++k)
            process_elem(p0[k], u0[k], t0[k], facc, cacc, bins);
        #pragma unroll
        for (int k = 0; k < 4; ++k)
            process_elem(p1[k], u1[k], t1[k], facc, cacc, bins);
    }
    if (i < n4) {
        f32x4 p0 = __builtin_nontemporal_load(p4 + i);
        f32x4 u0 = __builtin_nontemporal_load(u4 + i);
        i32x4 t0 = __builtin_nontemporal_load(t4 + i);
        #pragma unroll
        for (int k = 0; k < 4; ++k)
            process_elem(p0[k], u0[k], t0[k], facc, cacc, bins);
    }

    // scalar tail (n not multiple of 4)
    if (blockIdx.x == 0 && threadIdx.x == 0) {
        for (int j = n4 * 4; j < n; ++j)
            process_elem(p_hat[j], u_hat[j], targets[j], facc, cacc, bins);
    }

    // ---- block reduction of all 17 values ----
    float vals[NV];
    vals[0] = facc; vals[1] = cacc;
    #pragma unroll
    for (int j = 0; j < NB; ++j) vals[2 + j] = bins[j];

    #pragma unroll
    for (int off = 32; off > 0; off >>= 1) {
        #pragma unroll
        for (int j = 0; j < NV; ++j)
            vals[j] += __shfl_down(vals[j], off, 64);
    }

    __shared__ float lds[BLOCK / 64][NV];
    const int wave = threadIdx.x >> 6;
    const int lane = threadIdx.x & 63;
    if (lane == 0) {
        #pragma unroll
        for (int j = 0; j < NV; ++j) lds[wave][j] = vals[j];
    }
    __syncthreads();

    if (threadIdx.x < NV) {
        float s = 0.0f;
        #pragma unroll
        for (int w = 0; w < BLOCK / 64; ++w) s += lds[w][threadIdx.x];
        partials[threadIdx.x * grid + blockIdx.x] = s;
    }

    // ---- fused final reduction: last block to finish does it ----
    __threadfence();                       // release partials (device scope)
    __shared__ unsigned int amLast;
    if (threadIdx.x == 0)
        amLast = (atomicAdd(counter, 1u) == (unsigned int)(grid - 1)) ? 1u : 0u;
    __syncthreads();
    if (amLast == 0u) return;
    __threadfence();                       // acquire all blocks' partials

    float v[NV];
    #pragma unroll
    for (int j = 0; j < NV; ++j) {
        float s = 0.0f;
        for (int g = (int)threadIdx.x; g < grid; g += BLOCK)
            s += partials[j * grid + g];
        v[j] = s;
    }

    #pragma unroll
    for (int off = 32; off > 0; off >>= 1) {
        #pragma unroll
        for (int j = 0; j < NV; ++j)
            v[j] += __shfl_down(v[j], off, 64);
    }

    if (lane == 0) {   // lds reuse safe: all prior reads completed before the
        #pragma unroll // __syncthreads() above
        for (int j = 0; j < NV; ++j) lds[wave][j] = v[j];
    }
    __syncthreads();

    if (threadIdx.x == 0) {
        float s[NV];
        #pragma unroll
        for (int j = 0; j < NV; ++j) s[j] = 0.0f;
        for (int w = 0; w < BLOCK / 64; ++w)
            #pragma unroll
            for (int j = 0; j < NV; ++j) s[j] += lds[w][j];
        float e = 0.0f;
        #pragma unroll
        for (int b = 0; b < NB; ++b) e += fabsf(s[2 + b]);
        out[0] = (s[0] + 6.0f * s[1] + 5.0f * e) * inv_n;
    }
}

extern "C" void kernel_launch(void* const* d_in, const int* in_sizes, int n_in,
                              void* d_out, int out_size, void* d_ws, size_t ws_size,
                              hipStream_t stream) {
    const float* p = (const float*)d_in[0];
    const float* u = (const float*)d_in[1];
    const int*   t = (const int*)d_in[2];
    float* out = (float*)d_out;
    float* ws  = (float*)d_ws;

    const int n  = in_sizes[0];
    const int n4 = n / 4;

    // pick grid the workspace can hold (partials + counter)
    const int grid = (ws_size >= (size_t)(NV * BIGGRID + 1) * sizeof(float))
                         ? BIGGRID : 1024;
    float*        partials = ws;
    unsigned int* counter  = (unsigned int*)(ws + (size_t)NV * grid);

    // graph-safe counter reset (kernel, not hipMemsetAsync)
    fcl_init<<<1, 1, 0, stream>>>(counter);
    fcl_fused<<<grid, BLOCK, 0, stream>>>(p, u, t, partials, counter, out,
                                          1.0f / (float)n, n4, n, grid);
}

// Round 8
// 331.657 us; speedup vs baseline: 1.6077x; 1.6077x over previous
//
#include <hip/hip_runtime.h>

#define NB 15
#define NV 17          // focal, cp, 15 bins
#define BLOCK 256
#define GRID 1024      // 4 blocks/CU (LDS-limited), rounds = 16 exact, no tail

// ws layout: partials[j * GRID + block] j in [0,NV), then a 4-byte counter.
// j=0: focal sum, j=1: cp sum, j=2..16: per-bin sum(t - p)

typedef float f32x4 __attribute__((ext_vector_type(4)));
typedef int   i32x4 __attribute__((ext_vector_type(4)));

#define AS1 __attribute__((address_space(1)))
#define AS3 __attribute__((address_space(3)))

// fire-and-forget global->LDS DMA, 16B per lane; LDS dest = base + lane*16
__device__ __forceinline__ void gld16(const void* g, void* l) {
    __builtin_amdgcn_global_load_lds((const AS1 void*)g, (AS3 void*)l, 16, 0, 0);
}

__device__ __forceinline__ void process_elem(float pk, float uk, int tk,
                                             float& facc, float& cacc,
                                             float* bins)
{
    bool pos = (tk == 1);

    // focal: -alpha * (1-pt)^2 * ln(pt + 1e-12); ln2 folded into alpha
    float pt  = pos ? pk : 1.0f - pk;
    float om  = 1.0f - pt;
    float l2  = __log2f(pt + 1e-12f);
    float f   = om * om * l2;
    float na  = pos ? -0.69314718055994531f : -1.38629436111989062f;
    facc = fmaf(f, na, facc);

    // calibration penalty, gate rewritten on pt:
    //   pos: pk<0.7 <=> pt<0.7 ; neg: pk>0.7 <=> pt<0.3
    float thr = pos ? 0.7f : 0.3f;
    float s   = pos ? uk : 1.0f - uk;
    float pen = (pt < thr) ? s * s : 0.0f;
    cacc += pen;

    // ECE histogram into register bins (exact ceil form preserved)
    int b = (int)ceilf(pk * 15.0f) - 1;
    b = min(max(b, 0), NB - 1);
    float v = (pos ? 1.0f : 0.0f) - pk;
    #pragma unroll
    for (int j = 0; j < NB; ++j)
        bins[j] += (b == j) ? v : 0.0f;
}

__device__ __forceinline__ void process4(const f32x4& p, const f32x4& u,
                                         const i32x4& t,
                                         float& facc, float& cacc, float* bins)
{
    #pragma unroll
    for (int k = 0; k < 4; ++k)
        process_elem(p[k], u[k], t[k], facc, cacc, bins);
}

__global__ void fcl_init(unsigned int* __restrict__ counter)
{
    *counter = 0u;
}

__global__ __launch_bounds__(BLOCK) void fcl_fused(
    const float* __restrict__ p_hat,
    const float* __restrict__ u_hat,
    const int*   __restrict__ targets,
    float* __restrict__ partials,
    unsigned int* __restrict__ counter,
    float* __restrict__ out,
    float inv_n, int n4, int n, int grid)
{
    // triple-buffered per-wave staging: each wave stages ONLY its own 64
    // lanes' chunk and consumes only that -> NO barriers needed; ordering is
    // purely per-wave vmcnt. 3 streams x 3 bufs x 256 x 16B = 36.9 KB.
    __shared__ f32x4 sp[3][BLOCK];
    __shared__ f32x4 su[3][BLOCK];
    __shared__ i32x4 st[3][BLOCK];

    float bins[NB];
    #pragma unroll
    for (int j = 0; j < NB; ++j) bins[j] = 0.0f;
    float facc = 0.0f, cacc = 0.0f;

    const f32x4* __restrict__ p4 = (const f32x4*)p_hat;
    const f32x4* __restrict__ u4 = (const f32x4*)u_hat;
    const i32x4* __restrict__ t4 = (const i32x4*)targets;

    const int stride = grid * BLOCK;
    const int tid0   = blockIdx.x * BLOCK + threadIdx.x;
    const int rounds = n4 / stride;          // full rounds: all threads in-bounds
    const int wvbase = threadIdx.x & ~63;    // wave-uniform LDS chunk base

// stage round data for THIS wave into buffer `buf` (3 vmcnt ops)
#define STAGE(buf, idx)                                                        \
    {                                                                          \
        const int _i = (idx);                                                  \
        gld16(p4 + _i, &sp[buf][wvbase]);                                      \
        gld16(u4 + _i, &su[buf][wvbase]);                                      \
        gld16(t4 + _i, &st[buf][wvbase]);                                      \
    }

    int i = tid0;
    if (rounds > 0) {
        // prologue: fill depth-2 pipeline
        STAGE(0, i);
        if (rounds > 1) STAGE(1, i + stride);

        int cur = 0;
        for (int r = 0; r < rounds; ++r) {
            const int left = rounds - r;
            const int nxt  = (cur + 2 >= 3) ? cur - 1 : cur + 2;
            if (left > 2) {
                STAGE(nxt, i + 2 * stride);                     // 9 outstanding
                asm volatile("s_waitcnt vmcnt(6)" ::: "memory"); // round r landed
            } else if (left == 2) {
                asm volatile("s_waitcnt vmcnt(3)" ::: "memory");
            } else {
                asm volatile("s_waitcnt vmcnt(0)" ::: "memory");
            }
            __builtin_amdgcn_sched_barrier(0);

            f32x4 pv = sp[cur][threadIdx.x];
            f32x4 uv = su[cur][threadIdx.x];
            i32x4 tv = st[cur][threadIdx.x];
            process4(pv, uv, tv, facc, cacc, bins);

            cur = (cur + 1 == 3) ? 0 : cur + 1;
            i += stride;
        }
    }

    // remainder vec batches (n4 % stride != 0) -- plain loads, pipeline drained
    while (i < n4) {
        f32x4 p0 = p4[i]; f32x4 u0 = u4[i]; i32x4 t0 = t4[i];
        process4(p0, u0, t0, facc, cacc, bins);
        i += stride;
    }

    // scalar tail (n not multiple of 4)
    if (blockIdx.x == 0 && threadIdx.x == 0) {
        for (int j = n4 * 4; j < n; ++j)
            process_elem(p_hat[j], u_hat[j], targets[j], facc, cacc, bins);
    }

    // ---- block reduction of all 17 values ----
    float vals[NV];
    vals[0] = facc; vals[1] = cacc;
    #pragma unroll
    for (int j = 0; j < NB; ++j) vals[2 + j] = bins[j];

    #pragma unroll
    for (int off = 32; off > 0; off >>= 1) {
        #pragma unroll
        for (int j = 0; j < NV; ++j)
            vals[j] += __shfl_down(vals[j], off, 64);
    }

    __shared__ float lds[BLOCK / 64][NV];
    const int wave = threadIdx.x >> 6;
    const int lane = threadIdx.x & 63;
    if (lane == 0) {
        #pragma unroll
        for (int j = 0; j < NV; ++j) lds[wave][j] = vals[j];
    }
    __syncthreads();

    if (threadIdx.x < NV) {
        float s = 0.0f;
        #pragma unroll
        for (int w = 0; w < BLOCK / 64; ++w) s += lds[w][threadIdx.x];
        partials[threadIdx.x * grid + blockIdx.x] = s;
    }

    // ---- fused final reduction: last block to finish does it ----
    __threadfence();                       // release partials (device scope)
    __shared__ unsigned int amLast;
    if (threadIdx.x == 0)
        amLast = (atomicAdd(counter, 1u) == (unsigned int)(grid - 1)) ? 1u : 0u;
    __syncthreads();
    if (amLast == 0u) return;
    __threadfence();                       // acquire all blocks' partials

    float v[NV];
    #pragma unroll
    for (int j = 0; j < NV; ++j) {
        float s = 0.0f;
        for (int g = (int)threadIdx.x; g < grid; g += BLOCK)
            s += partials[j * grid + g];
        v[j] = s;
    }

    #pragma unroll
    for (int off = 32; off > 0; off >>= 1) {
        #pragma unroll
        for (int j = 0; j < NV; ++j)
            v[j] += __shfl_down(v[j], off, 64);
    }

    if (lane == 0) {   // lds reuse safe: prior reads completed before the
        #pragma unroll // __syncthreads() above
        for (int j = 0; j < NV; ++j) lds[wave][j] = v[j];
    }
    __syncthreads();

    if (threadIdx.x == 0) {
        float s[NV];
        #pragma unroll
        for (int j = 0; j < NV; ++j) s[j] = 0.0f;
        for (int w = 0; w < BLOCK / 64; ++w)
            #pragma unroll
            for (int j = 0; j < NV; ++j) s[j] += lds[w][j];
        float e = 0.0f;
        #pragma unroll
        for (int b = 0; b < NB; ++b) e += fabsf(s[2 + b]);
        out[0] = (s[0] + 6.0f * s[1] + 5.0f * e) * inv_n;
    }
}

extern "C" void kernel_launch(void* const* d_in, const int* in_sizes, int n_in,
                              void* d_out, int out_size, void* d_ws, size_t ws_size,
                              hipStream_t stream) {
    const float* p = (const float*)d_in[0];
    const float* u = (const float*)d_in[1];
    const int*   t = (const int*)d_in[2];
    float* out = (float*)d_out;
    float* ws  = (float*)d_ws;

    const int n  = in_sizes[0];
    const int n4 = n / 4;

    float*        partials = ws;
    unsigned int* counter  = (unsigned int*)(ws + (size_t)NV * GRID);

    // graph-safe counter reset (kernel, not hipMemsetAsync)
    fcl_init<<<1, 1, 0, stream>>>(counter);
    fcl_fused<<<GRID, BLOCK, 0, stream>>>(p, u, t, partials, counter, out,
                                          1.0f / (float)n, n4, n, GRID);
}